// Round 3
// baseline (163.000 us; speedup 1.0000x reference)
//
#include <hip/hip_runtime.h>
#include <hip/hip_bf16.h>

typedef __attribute__((ext_vector_type(8))) short short8;
typedef __attribute__((ext_vector_type(4))) short short4b;
typedef __attribute__((ext_vector_type(4))) float f32x4;

#define NBATCH 32
#define NT 512
#define NS 512
#define ND 1024
#define BM 128
#define BN 128
#define BK 64
#define NKSTEP (ND / BK) /* 16 */

__device__ __forceinline__ short f2bf(float f) {
    union { __hip_bfloat16 h; short s; } u;
    u.h = __float2bfloat16(f);
    return u.s;
}

// 128x128 output tile, 512 threads = 8 waves (2x4), each wave 64x32 via 4x2
// fragments of v_mfma_f32_16x16x32_bf16. Double-buffered LDS (one barrier per
// K-step) + DEPTH-2 global->reg pipeline with two register sets (even/odd):
// each tile's loads get ~2 MFMA phases + 2 barriers to complete, and the
// vmcnt wait before each LDS-store phase is counted (the other set's 8 loads
// stay in flight - never a full drain). f32 inputs are reg-staged, converted
// to bf16 into XOR-swizzled LDS; row sum-of-squares accumulated during
// staging (each element loaded exactly once per block -> norms are free).
// XCD-chunked block swizzle: 512 blocks, XCD k gets logical blocks
// [64k, 64k+64) = 4 whole batches -> L2 panel reuse.
__global__ __launch_bounds__(512, 4)
void paircos_mfma(const float* __restrict__ sup, const float* __restrict__ tgt,
                  float* __restrict__ out) {
    __shared__ __align__(16) short As[2][BM * BK]; // targets tiles
    __shared__ __align__(16) short Bs[2][BN * BK]; // supports tiles
    __shared__ float tn[BM];
    __shared__ float sn[BN];

    const int tid = threadIdx.x;
    // XCD-chunked bijective swizzle (512 % 8 == 0)
    const int l    = blockIdx.x;
    const int wgid = (l & 7) * 64 + (l >> 3);
    const int b    = wgid >> 4;        // batch
    const int til  = wgid & 15;        // tile within batch
    const int bt0  = (til >> 2) * BM;
    const int bs0  = (til & 3) * BN;

    // staging: thread covers rows {j*32 + rb : j=0..3}, float4-col c
    const int c  = tid & 15;  // 0..15
    const int rb = tid >> 4;  // 0..31

    const float* tb = tgt + (size_t)b * NT * ND + (size_t)(bt0 + rb) * ND + c * 4;
    const float* sb = sup + (size_t)b * NS * ND + (size_t)(bs0 + rb) * ND + c * 4;

    const int wave = tid >> 6;
    const int lane = tid & 63;
    const int wr  = (wave >> 2) * 64;  // 0 or 64
    const int wc  = (wave & 3) * 32;   // 0,32,64,96
    const int lhi = lane >> 4;         // 0..3 (k-group)
    const int llo = lane & 15;         // row/col within fragment

    f32x4 acc[4][2];
#pragma unroll
    for (int m = 0; m < 4; ++m)
#pragma unroll
        for (int n = 0; n < 2; ++n)
            acc[m][n] = (f32x4){0.f, 0.f, 0.f, 0.f};

    float sqA[4] = {0.f, 0.f, 0.f, 0.f};
    float sqB[4] = {0.f, 0.f, 0.f, 0.f};

    // two prefetch register sets (static names per rule #20)
    float4 rAe[4], rBe[4], rAo[4], rBo[4];

#define LOADT(RA, RB, KK)                                                      \
    do {                                                                       \
        const float* tb2 = tb + (KK) * BK;                                     \
        const float* sb2 = sb + (KK) * BK;                                     \
        _Pragma("unroll") for (int j = 0; j < 4; ++j) {                        \
            RA[j] = *reinterpret_cast<const float4*>(tb2 + (size_t)j * 32 * ND); \
            RB[j] = *reinterpret_cast<const float4*>(sb2 + (size_t)j * 32 * ND); \
        }                                                                      \
    } while (0)

#define STORET(RA, RB, BUF)                                                    \
    do {                                                                       \
        short* dA = As[BUF];                                                   \
        short* dB = Bs[BUF];                                                   \
        _Pragma("unroll") for (int j = 0; j < 4; ++j) {                        \
            const int row = j * 32 + rb;                                       \
            const int off = row * BK + ((c * 4) ^ ((row & 7) << 3));           \
            float4 a = RA[j];                                                  \
            sqA[j] = fmaf(a.x, a.x, fmaf(a.y, a.y, fmaf(a.z, a.z, fmaf(a.w, a.w, sqA[j])))); \
            short4b va = { f2bf(a.x), f2bf(a.y), f2bf(a.z), f2bf(a.w) };       \
            *reinterpret_cast<short4b*>(&dA[off]) = va;                        \
            float4 bb = RB[j];                                                 \
            sqB[j] = fmaf(bb.x, bb.x, fmaf(bb.y, bb.y, fmaf(bb.z, bb.z, fmaf(bb.w, bb.w, sqB[j])))); \
            short4b vb = { f2bf(bb.x), f2bf(bb.y), f2bf(bb.z), f2bf(bb.w) };   \
            *reinterpret_cast<short4b*>(&dB[off]) = vb;                        \
        }                                                                      \
    } while (0)

#define MFMA_PHASE(SAS, SBS)                                                   \
    do {                                                                       \
        const short* sAs = (SAS);                                              \
        const short* sBs = (SBS);                                              \
        _Pragma("unroll") for (int ks = 0; ks < 2; ++ks) {                     \
            short8 af[4], bf[2];                                               \
            const int kb = ks * 32 + lhi * 8;                                  \
            _Pragma("unroll") for (int m = 0; m < 4; ++m) {                    \
                const int row = wr + m * 16 + llo;                             \
                const int off = row * BK + (kb ^ ((row & 7) << 3));            \
                af[m] = *reinterpret_cast<const short8*>(&sAs[off]);           \
            }                                                                  \
            _Pragma("unroll") for (int n = 0; n < 2; ++n) {                    \
                const int row = wc + n * 16 + llo;                             \
                const int off = row * BK + (kb ^ ((row & 7) << 3));            \
                bf[n] = *reinterpret_cast<const short8*>(&sBs[off]);           \
            }                                                                  \
            _Pragma("unroll") for (int m = 0; m < 4; ++m)                      \
                _Pragma("unroll") for (int n = 0; n < 2; ++n)                  \
                    acc[m][n] = __builtin_amdgcn_mfma_f32_16x16x32_bf16(       \
                        af[m], bf[n], acc[m][n], 0, 0, 0);                     \
        }                                                                      \
    } while (0)

    // prologue: e <- tile0, o <- tile1; tile0 -> buf0; e <- tile2
    LOADT(rAe, rBe, 0);
    LOADT(rAo, rBo, 1);
    STORET(rAe, rBe, 0);
    LOADT(rAe, rBe, 2);
    __syncthreads(); // buf0 visible

    for (int kk = 0; kk < NKSTEP; kk += 2) {
        // even slot: tile kk in buf0; write tile kk+1 (o-set) into buf1
        STORET(rAo, rBo, 1); // kk+1 <= 15 always
        if (kk + 3 < NKSTEP) LOADT(rAo, rBo, kk + 3);
        MFMA_PHASE(As[0], Bs[0]);
        __syncthreads();
        // odd slot: tile kk+1 in buf1; write tile kk+2 (e-set) into buf0
        if (kk + 2 < NKSTEP) STORET(rAe, rBe, 0);
        if (kk + 4 < NKSTEP) LOADT(rAe, rBe, kk + 4);
        MFMA_PHASE(As[1], Bs[1]);
        __syncthreads();
    }

    // reduce row sum-of-squares across the 16 staging threads of each row
    // (16 contiguous, 16-aligned lanes -> xor<16 stays in-group)
#pragma unroll
    for (int d = 1; d < 16; d <<= 1) {
#pragma unroll
        for (int j = 0; j < 4; ++j) {
            sqA[j] += __shfl_xor(sqA[j], d);
            sqB[j] += __shfl_xor(sqB[j], d);
        }
    }
    if (c == 0) {
#pragma unroll
        for (int j = 0; j < 4; ++j) { // static index per rule #20
            tn[j * 32 + rb] = sqrtf(sqA[j]);
            sn[j * 32 + rb] = sqrtf(sqB[j]);
        }
    }
    __syncthreads();

    float* outp = out + (size_t)b * NT * NS;
#pragma unroll
    for (int m = 0; m < 4; ++m) {
        const int lr0 = wr + m * 16 + lhi * 4;
#pragma unroll
        for (int n = 0; n < 2; ++n) {
            const int lc = wc + n * 16 + llo;
            const float snv = sn[lc];
            const int col = bs0 + lc;
#pragma unroll
            for (int j = 0; j < 4; ++j) {
                const float denom = fmaxf(tn[lr0 + j] * snv, 1e-10f);
                outp[(size_t)(bt0 + lr0 + j) * NS + col] =
                    acc[m][n][j] / denom * 0.5f + 0.5f;
            }
        }
    }
}

extern "C" void kernel_launch(void* const* d_in, const int* in_sizes, int n_in,
                              void* d_out, int out_size, void* d_ws, size_t ws_size,
                              hipStream_t stream) {
    const float* sup = (const float*)d_in[0]; // supports [32,512,1024]
    const float* tgt = (const float*)d_in[1]; // targets  [32,512,1024]
    float* out = (float*)d_out;               // [32,512,512] f32
    (void)in_sizes; (void)n_in; (void)out_size; (void)d_ws; (void)ws_size;
    paircos_mfma<<<dim3(16 * NBATCH), 512, 0, stream>>>(sup, tgt, out);
}

// Round 4
// 70.125 us; speedup vs baseline: 2.3244x; 2.3244x over previous
//
#include <hip/hip_runtime.h>
#include <hip/hip_bf16.h>

typedef __attribute__((ext_vector_type(8))) short short8;
typedef __attribute__((ext_vector_type(4))) float f32x4;

#define NBATCH 32
#define NT 512
#define NS 512
#define ND 1024
#define BM 128
#define BN 128
#define BK2 32               /* f32 elements per K-step */
#define NK (ND / BK2)        /* 32 K-steps */
#define ROWB 128             /* bytes per LDS row: 32 f32 */
#define OPBYTES (BM * ROWB)  /* 16 KB per operand tile */
#define BUFBYTES (2 * OPBYTES)

__device__ __forceinline__ short f2bf(float f) {
    union { __hip_bfloat16 h; short s; } u;
    u.h = __float2bfloat16(f);
    return u.s;
}

__device__ __forceinline__ short8 cvt8(float4 a, float4 b) {
    short8 r;
    r[0] = f2bf(a.x); r[1] = f2bf(a.y); r[2] = f2bf(a.z); r[3] = f2bf(a.w);
    r[4] = f2bf(b.x); r[5] = f2bf(b.y); r[6] = f2bf(b.z); r[7] = f2bf(b.w);
    return r;
}

__device__ __forceinline__ float ssq8(float s, float4 a, float4 b) {
    s = fmaf(a.x, a.x, fmaf(a.y, a.y, fmaf(a.z, a.z, fmaf(a.w, a.w, s))));
    s = fmaf(b.x, b.x, fmaf(b.y, b.y, fmaf(b.z, b.z, fmaf(b.w, b.w, s))));
    return s;
}

#define GLDS16(G, S)                                                           \
    __builtin_amdgcn_global_load_lds(                                          \
        (const __attribute__((address_space(1))) void*)(G),                    \
        (__attribute__((address_space(3))) void*)(S), 16, 0, 0)

// 128x128 output tile, 512 threads = 8 waves (2x4), wave computes 64x32 via
// 4x2 fragments of v_mfma_f32_16x16x32_bf16, BK=32 f32 per step (one MFMA-k).
// m97 structure: raw f32 staged via global_load_lds (fire-and-forget DMA, no
// prefetch VGPRs, the only wait is the pre-barrier drain which overlaps the
// compute phase and the 2nd resident block). LDS dest is linear (HW rule);
// the XOR swizzle (16B units, u ^= row&7) is applied to the per-lane GLOBAL
// source address on the write side and to the ds_read address on the read
// side (rule #21 both-sides). f32 frags are converted to bf16 at read time;
// row sum-of-squares for the cosine denominator is accumulated from the f32
// fragments by designated waves (wc==0 -> A rows, wr==0 -> B rows) -> norms
// still require no extra pass over the inputs.
__global__ __launch_bounds__(512, 4)
void paircos_mfma(const float* __restrict__ sup, const float* __restrict__ tgt,
                  float* __restrict__ out) {
    __shared__ __align__(1024) unsigned char ldsbuf[2][BUFBYTES];
    __shared__ float tn[BM];
    __shared__ float sn[BN];

    const int tid = threadIdx.x;
    const int b   = blockIdx.y;
    const int bt0 = (blockIdx.x >> 2) * BM;
    const int bs0 = (blockIdx.x & 3)  * BN;

    const float* tA = tgt + (size_t)b * NT * ND + (size_t)bt0 * ND; // targets panel
    const float* tB = sup + (size_t)b * NS * ND + (size_t)bs0 * ND; // supports panel

    // staging: lane's linear LDS slot L = tid*16 (+ i*8192) -> row = L>>7,
    // lds unit = tid&7; global unit = ldsunit ^ (row&7) (inverse swizzle)
    const int srow = tid >> 3;                        // 0..63 (i=1 adds 64)
    const int sug  = (tid & 7) ^ (srow & 7);
    const float* gA = tA + (size_t)srow * ND + sug * 4;
    const float* gB = tB + (size_t)srow * ND + sug * 4;

    const int wave = tid >> 6;
    const int lane = tid & 63;
    const int wr  = (wave >> 2) * 64;  // 0 or 64
    const int wc  = (wave & 3) * 32;   // 0,32,64,96
    const int lhi = lane >> 4;         // 0..3 (k-group of 8)
    const int llo = lane & 15;         // row/col within fragment

    f32x4 acc[4][2];
#pragma unroll
    for (int m = 0; m < 4; ++m)
#pragma unroll
        for (int n = 0; n < 2; ++n)
            acc[m][n] = (f32x4){0.f, 0.f, 0.f, 0.f};

    float sqa[4] = {0.f, 0.f, 0.f, 0.f};
    float sqb[2] = {0.f, 0.f};

#define STAGE(P, KK)                                                           \
    do {                                                                       \
        unsigned char* dst = &ldsbuf[P][0] + wave * 1024;                      \
        const float* ga = gA + (KK) * BK2;                                     \
        const float* gb = gB + (KK) * BK2;                                     \
        GLDS16(ga,            dst);                                            \
        GLDS16(ga + 64 * ND,  dst + 8192);                                     \
        GLDS16(gb,            dst + OPBYTES);                                  \
        GLDS16(gb + 64 * ND,  dst + OPBYTES + 8192);                           \
    } while (0)

#define COMPUTE(P)                                                             \
    do {                                                                       \
        const unsigned char* aB_ = &ldsbuf[P][0];                              \
        const unsigned char* bB_ = &ldsbuf[P][OPBYTES];                        \
        short8 af[4]; short8 bfr[2];                                           \
        _Pragma("unroll") for (int m = 0; m < 4; ++m) {                        \
            const int row = wr + m * 16 + llo;                                 \
            const int sw = row & 7;                                            \
            const float4 q0 = *(const float4*)(aB_ + row * ROWB + (((lhi * 2    ) ^ sw) << 4)); \
            const float4 q1 = *(const float4*)(aB_ + row * ROWB + (((lhi * 2 + 1) ^ sw) << 4)); \
            if (wc == 0) sqa[m] = ssq8(sqa[m], q0, q1);                        \
            af[m] = cvt8(q0, q1);                                              \
        }                                                                      \
        _Pragma("unroll") for (int n = 0; n < 2; ++n) {                        \
            const int row = wc + n * 16 + llo;                                 \
            const int sw = row & 7;                                            \
            const float4 q0 = *(const float4*)(bB_ + row * ROWB + (((lhi * 2    ) ^ sw) << 4)); \
            const float4 q1 = *(const float4*)(bB_ + row * ROWB + (((lhi * 2 + 1) ^ sw) << 4)); \
            if (wr == 0) sqb[n] = ssq8(sqb[n], q0, q1);                        \
            bfr[n] = cvt8(q0, q1);                                             \
        }                                                                      \
        _Pragma("unroll") for (int m = 0; m < 4; ++m)                          \
            _Pragma("unroll") for (int n = 0; n < 2; ++n)                      \
                acc[m][n] = __builtin_amdgcn_mfma_f32_16x16x32_bf16(           \
                    af[m], bfr[n], acc[m][n], 0, 0, 0);                        \
    } while (0)

    STAGE(0, 0);
    __syncthreads(); // tile 0 resident

    int cur = 0;
#pragma unroll 2
    for (int kk = 0; kk < NK; ++kk) {
        if (kk + 1 < NK) STAGE(cur ^ 1, kk + 1); // fire-and-forget DMA
        COMPUTE(cur);                            // hides the DMA latency
        __syncthreads();                         // drain vmcnt+lgkm, flip
        cur ^= 1;
    }

    // norms: reduce each row's partial sum over the 4 lhi k-slices
    if (wc == 0) { // waves 0,4: A rows wr..wr+63
#pragma unroll
        for (int m = 0; m < 4; ++m) {
            float v = sqa[m];
            v += __shfl_xor(v, 16);
            v += __shfl_xor(v, 32);
            if (lhi == 0) tn[wr + m * 16 + llo] = sqrtf(v);
        }
    }
    if (wr == 0) { // waves 0-3: B rows wc..wc+31
#pragma unroll
        for (int n = 0; n < 2; ++n) {
            float v = sqb[n];
            v += __shfl_xor(v, 16);
            v += __shfl_xor(v, 32);
            if (lhi == 0) sn[wc + n * 16 + llo] = sqrtf(v);
        }
    }
    __syncthreads();

    float* outp = out + (size_t)b * NT * NS;
#pragma unroll
    for (int m = 0; m < 4; ++m) {
        const int lr0 = wr + m * 16 + lhi * 4;
#pragma unroll
        for (int n = 0; n < 2; ++n) {
            const int lc = wc + n * 16 + llo;
            const float snv = sn[lc];
            const int col = bs0 + lc;
#pragma unroll
            for (int j = 0; j < 4; ++j) {
                const float denom = fmaxf(tn[lr0 + j] * snv, 1e-10f);
                outp[(size_t)(bt0 + lr0 + j) * NS + col] =
                    acc[m][n][j] / denom * 0.5f + 0.5f;
            }
        }
    }
}

extern "C" void kernel_launch(void* const* d_in, const int* in_sizes, int n_in,
                              void* d_out, int out_size, void* d_ws, size_t ws_size,
                              hipStream_t stream) {
    const float* sup = (const float*)d_in[0]; // supports [32,512,1024]
    const float* tgt = (const float*)d_in[1]; // targets  [32,512,1024]
    float* out = (float*)d_out;               // [32,512,512] f32
    (void)in_sizes; (void)n_in; (void)out_size; (void)d_ws; (void)ws_size;
    dim3 grid(16, NBATCH, 1); // x: 4x4 output tiles, y: batch
    paircos_mfma<<<grid, 512, 0, stream>>>(sup, tgt, out);
}

// Round 5
// 39.673 us; speedup vs baseline: 4.1086x; 1.7676x over previous
//
#include <hip/hip_runtime.h>
#include <hip/hip_bf16.h>

typedef __attribute__((ext_vector_type(8))) short short8;
typedef __attribute__((ext_vector_type(4))) short short4b;
typedef __attribute__((ext_vector_type(4))) float f32x4;

#define NBATCH 32
#define NT 512
#define NS 512
#define ND 1024
#define BM 128
#define BN 128
#define BK 32                /* f32/bf16 elems per K-step */
#define NK (ND / BK)         /* 32 K-steps */

__device__ __forceinline__ short f2bf(float f) {
    union { __hip_bfloat16 h; short s; } u;
    u.h = __float2bfloat16(f);
    return u.s;
}

__device__ __forceinline__ short4b cvt4(float4 a) {
    short4b r;
    r[0] = f2bf(a.x); r[1] = f2bf(a.y); r[2] = f2bf(a.z); r[3] = f2bf(a.w);
    return r;
}

__device__ __forceinline__ float ssq4(float s, float4 a) {
    return fmaf(a.x, a.x, fmaf(a.y, a.y, fmaf(a.z, a.z, fmaf(a.w, a.w, s))));
}

// 128x128 tile, 512 threads = 8 waves (2x4), wave = 64x32 out via 4x2 frags
// of v_mfma_f32_16x16x32_bf16, BK=32 (one MFMA k-depth per step).
// bf16 staged in LDS (convert ONCE per element during staging; halves the
// LDS port time vs f32-in-LDS r4). DEPTH-2 global->reg pipeline: two reg
// sets (e/o) of 4 float4 each; a set's loads are issued 2 full phases before
// their vmcnt wait at STORET. Raw s_barrier + explicit lgkmcnt(0) fence (no
// __syncthreads in the K-loop) so the compiler never drains vmcnt at the
// barrier - in-flight loads span phases (T4 counted-wait discipline, m201).
// LDS rows are 32 bf16 = 64B = 4x16B units; swizzle u' = (u + (row>>1)) & 3
// applied on BOTH the ds_write and ds_read sides: frag reads are 2-way
// (free), staging writes conflict-free per 16-lane phase. Row sum-of-squares
// accumulated in f32 during staging (each element staged exactly once ->
// norms free). XCD-chunked 1D grid: XCD k owns 64 consecutive logical wgs
// = 4 whole batches -> L2/L3 panel reuse.
__global__ __launch_bounds__(512, 4)
void paircos_mfma(const float* __restrict__ sup, const float* __restrict__ tgt,
                  float* __restrict__ out) {
    __shared__ __align__(16) short As[2][BM * BK]; // targets tiles (8KB each)
    __shared__ __align__(16) short Bs[2][BN * BK]; // supports tiles
    __shared__ float tn[BM];
    __shared__ float sn[BN];

    const int tid = threadIdx.x;
    // XCD-chunked bijective swizzle (512 blocks, 512 % 8 == 0)
    const int l    = blockIdx.x;
    const int wgid = (l & 7) * 64 + (l >> 3);
    const int b    = wgid >> 4;
    const int til  = wgid & 15;
    const int bt0  = (til >> 2) * BM;
    const int bs0  = (til & 3) * BN;

    // staging: thread owns float4-col c8 (0..7) of rows r0 and r0+64
    const int c8 = tid & 7;
    const int r0 = tid >> 3; // 0..63

    const float* gA = tgt + (size_t)b * NT * ND + (size_t)(bt0 + r0) * ND + c8 * 4;
    const float* gB = sup + (size_t)b * NS * ND + (size_t)(bs0 + r0) * ND + c8 * 4;

    const int wave = tid >> 6;
    const int lane = tid & 63;
    const int wr  = (wave >> 2) * 64;  // 0 or 64
    const int wc  = (wave & 3) * 32;   // 0,32,64,96
    const int lhi = lane >> 4;         // 0..3 (k-group of 8)
    const int llo = lane & 15;

    f32x4 acc[4][2];
#pragma unroll
    for (int m = 0; m < 4; ++m)
#pragma unroll
        for (int n = 0; n < 2; ++n)
            acc[m][n] = (f32x4){0.f, 0.f, 0.f, 0.f};

    float sqa0 = 0.f, sqa1 = 0.f, sqb0 = 0.f, sqb1 = 0.f;

    // two prefetch register sets, static names (rule #20)
    float4 eA0, eA1, eB0, eB1, oA0, oA1, oB0, oB1;

    // LDS staging offsets (shorts): row*32 + u'*8 + (c8&1)*4,
    // u' = ((c8>>1) + (row>>1)) & 3 ; note (r0+64)>>1 ≡ r0>>1 (mod 4) shift 32
    const int u0   = ((c8 >> 1) + (r0 >> 1)) & 3;
    const int off0 = r0 * BK + u0 * 8 + (c8 & 1) * 4;
    const int off1 = (r0 + 64) * BK + u0 * 8 + (c8 & 1) * 4;

#define LOADT(A0, A1, B0, B1, KK)                                              \
    do {                                                                       \
        A0 = *reinterpret_cast<const float4*>(gA + (KK) * BK);                 \
        A1 = *reinterpret_cast<const float4*>(gA + (KK) * BK + 64 * ND);       \
        B0 = *reinterpret_cast<const float4*>(gB + (KK) * BK);                 \
        B1 = *reinterpret_cast<const float4*>(gB + (KK) * BK + 64 * ND);       \
    } while (0)

#define STORET(A0, A1, B0, B1, P)                                              \
    do {                                                                       \
        sqa0 = ssq4(sqa0, A0); *reinterpret_cast<short4b*>(&As[P][off0]) = cvt4(A0); \
        sqa1 = ssq4(sqa1, A1); *reinterpret_cast<short4b*>(&As[P][off1]) = cvt4(A1); \
        sqb0 = ssq4(sqb0, B0); *reinterpret_cast<short4b*>(&Bs[P][off0]) = cvt4(B0); \
        sqb1 = ssq4(sqb1, B1); *reinterpret_cast<short4b*>(&Bs[P][off1]) = cvt4(B1); \
    } while (0)

#define COMPUTE(P)                                                             \
    do {                                                                       \
        short8 af[4], bfr[2];                                                  \
        _Pragma("unroll") for (int m = 0; m < 4; ++m) {                        \
            const int row = wr + m * 16 + llo;                                 \
            const int off = row * BK + (((lhi + (row >> 1)) & 3) * 8);         \
            af[m] = *reinterpret_cast<const short8*>(&As[P][off]);             \
        }                                                                      \
        _Pragma("unroll") for (int n = 0; n < 2; ++n) {                        \
            const int row = wc + n * 16 + llo;                                 \
            const int off = row * BK + (((lhi + (row >> 1)) & 3) * 8);         \
            bfr[n] = *reinterpret_cast<const short8*>(&Bs[P][off]);            \
        }                                                                      \
        _Pragma("unroll") for (int m = 0; m < 4; ++m)                          \
            _Pragma("unroll") for (int n = 0; n < 2; ++n)                      \
                acc[m][n] = __builtin_amdgcn_mfma_f32_16x16x32_bf16(           \
                    af[m], bfr[n], acc[m][n], 0, 0, 0);                        \
    } while (0)

    // fence: make ds_writes visible, pin LDS ops to this side, then barrier.
    // No vmcnt drain here - global loads for the reg sets stay in flight.
#define PHASE_FENCE()                                                          \
    do {                                                                       \
        asm volatile("s_waitcnt lgkmcnt(0)" ::: "memory");                     \
        __builtin_amdgcn_s_barrier();                                          \
        asm volatile("" ::: "memory");                                         \
    } while (0)

    // prologue: tile0 -> buf0; e <- tile1, o <- tile2
    LOADT(eA0, eA1, eB0, eB1, 0);
    STORET(eA0, eA1, eB0, eB1, 0);
    LOADT(eA0, eA1, eB0, eB1, 1);
    LOADT(oA0, oA1, oB0, oB1, 2);
    PHASE_FENCE();

    for (int k = 0; k < NK; k += 2) {
        // even phase: MFMA on buf0 (tile k); e holds tile k+1 -> buf1
        STORET(eA0, eA1, eB0, eB1, 1);           // waits only e-loads (issued k-2)
        if (k + 3 < NK) LOADT(eA0, eA1, eB0, eB1, k + 3);
        COMPUTE(0);
        PHASE_FENCE();
        // odd phase: MFMA on buf1 (tile k+1); o holds tile k+2 -> buf0
        if (k + 2 < NK) STORET(oA0, oA1, oB0, oB1, 0);
        if (k + 4 < NK) LOADT(oA0, oA1, oB0, oB1, k + 4);
        COMPUTE(1);
        PHASE_FENCE();
    }

    // norms: reduce each row's sumsq over the 8 c8-threads (lanes sharing
    // lane>>3: xor 1,2,4 stays in-group)
#pragma unroll
    for (int d = 1; d < 8; d <<= 1) {
        sqa0 += __shfl_xor(sqa0, d);
        sqa1 += __shfl_xor(sqa1, d);
        sqb0 += __shfl_xor(sqb0, d);
        sqb1 += __shfl_xor(sqb1, d);
    }
    if (c8 == 0) {
        tn[r0]      = sqrtf(sqa0);
        tn[r0 + 64] = sqrtf(sqa1);
        sn[r0]      = sqrtf(sqb0);
        sn[r0 + 64] = sqrtf(sqb1);
    }
    __syncthreads();

    float* outp = out + (size_t)b * NT * NS;
#pragma unroll
    for (int m = 0; m < 4; ++m) {
        const int lr0 = wr + m * 16 + lhi * 4;
#pragma unroll
        for (int n = 0; n < 2; ++n) {
            const int lc = wc + n * 16 + llo;
            const float snv = sn[lc];
            const int col = bs0 + lc;
#pragma unroll
            for (int j = 0; j < 4; ++j) {
                const float denom = fmaxf(tn[lr0 + j] * snv, 1e-10f);
                outp[(size_t)(bt0 + lr0 + j) * NS + col] =
                    acc[m][n][j] / denom * 0.5f + 0.5f;
            }
        }
    }
}

extern "C" void kernel_launch(void* const* d_in, const int* in_sizes, int n_in,
                              void* d_out, int out_size, void* d_ws, size_t ws_size,
                              hipStream_t stream) {
    const float* sup = (const float*)d_in[0]; // supports [32,512,1024]
    const float* tgt = (const float*)d_in[1]; // targets  [32,512,1024]
    float* out = (float*)d_out;               // [32,512,512] f32
    (void)in_sizes; (void)n_in; (void)out_size; (void)d_ws; (void)ws_size;
    paircos_mfma<<<dim3(16 * NBATCH), 512, 0, stream>>>(sup, tgt, out);
}